// Round 11
// baseline (58.155 us; speedup 1.0000x reference)
//
#include <hip/hip_runtime.h>

#ifndef __has_builtin
#define __has_builtin(x) 0
#endif

#if __has_builtin(__builtin_amdgcn_exp2f)
#define EXP2F(x) __builtin_amdgcn_exp2f(x)
#else
#define EXP2F(x) exp2f(x)
#endif
#if __has_builtin(__builtin_amdgcn_rcpf)
#define RCPF(x) __builtin_amdgcn_rcpf(x)
#else
#define RCPF(x) (1.0f / (x))
#endif

static constexpr int NB = 4, NQ = 512, NK = 512, DD = 512, HH = 128, DV = 512;
static constexpr float MASKV = -1e6f;
static constexpr float C2LOG2E = 2.885390081777926814f;  // 2*log2(e)

typedef __attribute__((ext_vector_type(8))) short bf16x8;
typedef __attribute__((ext_vector_type(4))) float f32x4;

__device__ __forceinline__ unsigned short f2bf(float x) {  // RNE f32->bf16
  unsigned int u = __float_as_uint(x);
  u += 0x7FFFu + ((u >> 16) & 1u);
  return (unsigned short)(u >> 16);
}

// ---------------------------------------------------------------------------
// K1: 512 blocks.
//   bid 0..255   : projection GEMM tile (128 rows x 128 h, one 64-k split).
//                  A staged TRANSPOSED (aT[64k][128r]) so inner-loop A reads
//                  are b128 (2 LDS instrs) instead of 4 scalars. 8x8 micro.
//   bid 256..511 : V transpose -> Vt[b][v][k] bf16 (R10-proven).
// ---------------------------------------------------------------------------
__global__ __launch_bounds__(256) void proj_vt_kernel(
    const float* __restrict__ queries, const float* __restrict__ keys,
    const float* __restrict__ Wq, const float* __restrict__ Wk,
    const float* __restrict__ values, const int* __restrict__ valid_lens,
    float* __restrict__ projpart, unsigned short* __restrict__ Vt) {
  __shared__ __align__(16) char smem[65536];
  const int bid = blockIdx.x;
  const int t = threadIdx.x;

  if (bid < 256) {
    const int mt = bid >> 3;      // 0..31 row-tile
    const int ks = bid & 7;       // k-split
    const int row0 = mt << 7;     // 0..3968
    const int k0 = ks << 6;
    const float* inb;
    const float* W;
    if (row0 >= 2048) {
      const int local = row0 - 2048;
      if ((local & 511) >= valid_lens[local >> 9]) return;  // masked tile
      inb = keys + (size_t)local * DD;
      W = Wk;
    } else {
      inb = queries + (size_t)row0 * DD;
      W = Wq;
    }
    float* aT = reinterpret_cast<float*>(smem);            // [64][128] k-major
    float* Wt = reinterpret_cast<float*>(smem + 32768);    // [64][128]

    // stage A transposed: lane reads one float4 from row r (row-scatter
    // global), writes 4 consecutive-k scalars at column r (conflict-free:
    // consecutive lanes -> consecutive r -> consecutive banks).
#pragma unroll
    for (int f = 0; f < 8; ++f) {
      const int idx = t + (f << 8);
      const int r = idx & 127;
      const int c4 = (idx >> 7) << 2;  // 0,4,...,60
      const float4 v = *reinterpret_cast<const float4*>(inb + (size_t)r * DD + k0 + c4);
      aT[(c4 + 0) * 128 + r] = v.x;
      aT[(c4 + 1) * 128 + r] = v.y;
      aT[(c4 + 2) * 128 + r] = v.z;
      aT[(c4 + 3) * 128 + r] = v.w;
    }
    // stage W linear (coalesced b128 both sides)
#pragma unroll
    for (int f = 0; f < 8; ++f) {
      const int idx = t + (f << 8);
      const int dk = idx >> 5, c4 = (idx & 31) << 2;
      *reinterpret_cast<float4*>(Wt + dk * 128 + c4) =
          *reinterpret_cast<const float4*>(W + (size_t)(k0 + dk) * HH + c4);
    }
    __syncthreads();

    const int hg = t & 15;   // h-cols hg*8..+7
    const int rg = t >> 4;   // rows  rg*8..+7
    float acc[8][8];
#pragma unroll
    for (int i = 0; i < 8; ++i)
#pragma unroll
      for (int j = 0; j < 8; ++j) acc[i][j] = 0.f;

#pragma unroll 8
    for (int dk = 0; dk < 64; ++dk) {
      const float4 a0 = *reinterpret_cast<const float4*>(aT + dk * 128 + (rg << 3));
      const float4 a1 = *reinterpret_cast<const float4*>(aT + dk * 128 + (rg << 3) + 4);
      const float4 b0 = *reinterpret_cast<const float4*>(Wt + dk * 128 + (hg << 3));
      const float4 b1 = *reinterpret_cast<const float4*>(Wt + dk * 128 + (hg << 3) + 4);
      const float av[8] = {a0.x, a0.y, a0.z, a0.w, a1.x, a1.y, a1.z, a1.w};
      const float bv[8] = {b0.x, b0.y, b0.z, b0.w, b1.x, b1.y, b1.z, b1.w};
#pragma unroll
      for (int i = 0; i < 8; ++i)
#pragma unroll
        for (int j = 0; j < 8; ++j) acc[i][j] = fmaf(av[i], bv[j], acc[i][j]);
    }

    float* pb = projpart + ((size_t)ks << 19) + (size_t)row0 * HH;
#pragma unroll
    for (int i = 0; i < 8; ++i) {
      float* rowp = pb + (size_t)((rg << 3) + i) * HH + (hg << 3);
      *reinterpret_cast<float4*>(rowp) =
          make_float4(acc[i][0], acc[i][1], acc[i][2], acc[i][3]);
      *reinterpret_cast<float4*>(rowp + 4) =
          make_float4(acc[i][4], acc[i][5], acc[i][6], acc[i][7]);
    }
  } else {
    // V transpose (R10-proven)
    unsigned short (*tl)[72] = reinterpret_cast<unsigned short (*)[72]>(smem);
    const int vb = bid - 256;
    const int b = vb >> 6;
    const int tile = vb & 63;
    const int k0 = (tile >> 3) << 6;
    const int v0 = (tile & 7) << 6;
    const int kr = t >> 4, c4 = (t & 15) << 2;
#pragma unroll
    for (int pp = 0; pp < 4; ++pp) {
      const int k = kr + (pp << 4);
      const float4 v = *reinterpret_cast<const float4*>(
          values + ((size_t)(b * NK + k0 + k)) * DV + v0 + c4);
      tl[k][c4 + 0] = f2bf(v.x); tl[k][c4 + 1] = f2bf(v.y);
      tl[k][c4 + 2] = f2bf(v.z); tl[k][c4 + 3] = f2bf(v.w);
    }
    __syncthreads();
    const int vr = t >> 2, seg = t & 3;
    unsigned int pk[8];
#pragma unroll
    for (int i = 0; i < 8; ++i) {
      const int kc = (seg << 4) + (i << 1);
      pk[i] = (unsigned int)tl[kc][vr] | ((unsigned int)tl[kc + 1][vr] << 16);
    }
    unsigned short* dst = Vt + ((size_t)(b * NK + v0 + vr)) * NK + k0 + (seg << 4);
    *reinterpret_cast<uint4*>(dst) = make_uint4(pk[0], pk[1], pk[2], pk[3]);
    *reinterpret_cast<uint4*>(dst + 8) = make_uint4(pk[4], pk[5], pk[6], pk[7]);
  }
}

// ---------------------------------------------------------------------------
// K2: reduce the 8 K-split partials + exp2 transform. 512 blocks.
//   bid 0..255   -> eq[row][h]         (flat)
//   bid 256..511 -> ekT4[b][h4][k][4]  (transposed; masked rows skip)
// ---------------------------------------------------------------------------
__global__ __launch_bounds__(256) void reduce_kernel(
    const float* __restrict__ projpart, const int* __restrict__ valid_lens,
    float* __restrict__ eq, float* __restrict__ ekT4) {
  const int bid = blockIdx.x;
  const int t = threadIdx.x;
  const float4* p = reinterpret_cast<const float4*>(projpart);
  if (bid < 256) {
    const int i = bid * 256 + t;  // float4 idx into q-half (65536)
    float4 s = p[i];
#pragma unroll
    for (int j = 1; j < 8; ++j) {
      const float4 v = p[i + j * 131072];
      s.x += v.x; s.y += v.y; s.z += v.z; s.w += v.w;
    }
    float4 r;
    r.x = EXP2F(s.x * C2LOG2E);
    r.y = EXP2F(s.y * C2LOG2E);
    r.z = EXP2F(s.z * C2LOG2E);
    r.w = EXP2F(s.w * C2LOG2E);
    reinterpret_cast<float4*>(eq)[i] = r;
  } else {
    const int j = (bid - 256) * 256 + t;  // float4 idx in k-half
    const int rl = j >> 5;                // local key row 0..2047
    const int b = rl >> 9, k = rl & 511;
    if (k >= valid_lens[b]) return;       // masked: never read downstream
    const int h4 = j & 31;
    float4 s = p[65536 + j];
#pragma unroll
    for (int jj = 1; jj < 8; ++jj) {
      const float4 v = p[65536 + j + jj * 131072];
      s.x += v.x; s.y += v.y; s.z += v.z; s.w += v.w;
    }
    float4 r;
    r.x = EXP2F(s.x * C2LOG2E);
    r.y = EXP2F(s.y * C2LOG2E);
    r.z = EXP2F(s.z * C2LOG2E);
    r.w = EXP2F(s.w * C2LOG2E);
    *reinterpret_cast<float4*>(ekT4 + ((((size_t)b * 32 + h4) << 9) + k) * 4) = r;
  }
}

// ---------------------------------------------------------------------------
// K3: scores + masked softmax, 1024 threads, ZERO LDS in the inner loop:
// eq/Wv reads are wave-uniform -> compiler scalarizes to s_load (scalar pipe),
// freeing the LDS port. Inner = 1 coalesced e4 load + 16x(fma,rcp,fma).
// Block = (b, 4 q-rows), 512 blocks; thread = (key kk, h-half hh).
// ---------------------------------------------------------------------------
__global__ __launch_bounds__(1024) void scores_softmax_kernel(
    const float* __restrict__ eq, const float* __restrict__ ekT4,
    const float* __restrict__ Wv, const int* __restrict__ valid_lens,
    unsigned short* __restrict__ attnQ) {
  const int b = blockIdx.x >> 7;
  const int q0 = (blockIdx.x & 127) << 2;
  const int t = threadIdx.x;
  const int kk = t & 511, hh = t >> 9;

  __shared__ __align__(16) float scp[2][4][NK];  // 16 KB partials

  const int vl = valid_lens[b];
  float s0 = 0.f, s1 = 0.f, s2 = 0.f, s3 = 0.f;

  if (kk < vl) {
    const float* ekb4 = ekT4 + (((size_t)(b * 32 + hh * 16) << 9) + kk) * 4;
    const float* qrow0 = eq + ((size_t)(b * NQ + q0 + 0)) * HH;
    const float* qrow1 = eq + ((size_t)(b * NQ + q0 + 1)) * HH;
    const float* qrow2 = eq + ((size_t)(b * NQ + q0 + 2)) * HH;
    const float* qrow3 = eq + ((size_t)(b * NQ + q0 + 3)) * HH;
#pragma unroll 4
    for (int i = 0; i < 16; ++i) {
      const float4 e4 = *reinterpret_cast<const float4*>(ekb4 + ((size_t)i << 11));
      const int h = (hh * 16 + i) << 2;
      const float4 w4 = *reinterpret_cast<const float4*>(Wv + h);     // uniform -> s_load
      const float4 qa = *reinterpret_cast<const float4*>(qrow0 + h);  // uniform -> s_load
      const float4 qb = *reinterpret_cast<const float4*>(qrow1 + h);
      const float4 qc = *reinterpret_cast<const float4*>(qrow2 + h);
      const float4 qd = *reinterpret_cast<const float4*>(qrow3 + h);
      float d, r;
      d = fmaf(qa.x, e4.x, 1.f); r = RCPF(d); s0 = fmaf(w4.x, r, s0);
      d = fmaf(qa.y, e4.y, 1.f); r = RCPF(d); s0 = fmaf(w4.y, r, s0);
      d = fmaf(qa.z, e4.z, 1.f); r = RCPF(d); s0 = fmaf(w4.z, r, s0);
      d = fmaf(qa.w, e4.w, 1.f); r = RCPF(d); s0 = fmaf(w4.w, r, s0);
      d = fmaf(qb.x, e4.x, 1.f); r = RCPF(d); s1 = fmaf(w4.x, r, s1);
      d = fmaf(qb.y, e4.y, 1.f); r = RCPF(d); s1 = fmaf(w4.y, r, s1);
      d = fmaf(qb.z, e4.z, 1.f); r = RCPF(d); s1 = fmaf(w4.z, r, s1);
      d = fmaf(qb.w, e4.w, 1.f); r = RCPF(d); s1 = fmaf(w4.w, r, s1);
      d = fmaf(qc.x, e4.x, 1.f); r = RCPF(d); s2 = fmaf(w4.x, r, s2);
      d = fmaf(qc.y, e4.y, 1.f); r = RCPF(d); s2 = fmaf(w4.y, r, s2);
      d = fmaf(qc.z, e4.z, 1.f); r = RCPF(d); s2 = fmaf(w4.z, r, s2);
      d = fmaf(qc.w, e4.w, 1.f); r = RCPF(d); s2 = fmaf(w4.w, r, s2);
      d = fmaf(qd.x, e4.x, 1.f); r = RCPF(d); s3 = fmaf(w4.x, r, s3);
      d = fmaf(qd.y, e4.y, 1.f); r = RCPF(d); s3 = fmaf(w4.y, r, s3);
      d = fmaf(qd.z, e4.z, 1.f); r = RCPF(d); s3 = fmaf(w4.z, r, s3);
      d = fmaf(qd.w, e4.w, 1.f); r = RCPF(d); s3 = fmaf(w4.w, r, s3);
    }
  }
  scp[hh][0][kk] = s0;
  scp[hh][1][kk] = s1;
  scp[hh][2][kk] = s2;
  scp[hh][3][kk] = s3;
  __syncthreads();

  // softmax: waves 0..3 (t<256) handle q-rows 0..3, combining the h-halves
  if (t < 256) {
    const int w = t >> 6, l = t & 63;
    float v[8];
#pragma unroll
    for (int j = 0; j < 8; ++j) {
      const int k = l + (j << 6);
      const float sv = scp[0][w][k] + scp[1][w][k];
      v[j] = (k < vl) ? (-2.f * sv) : MASKV;
    }
    float m = v[0];
#pragma unroll
    for (int j = 1; j < 8; ++j) m = fmaxf(m, v[j]);
#pragma unroll
    for (int off = 32; off > 0; off >>= 1) m = fmaxf(m, __shfl_xor(m, off, 64));
    float p[8], sum = 0.f;
#pragma unroll
    for (int j = 0; j < 8; ++j) {
      p[j] = __expf(v[j] - m);  // masked: underflows to exactly 0
      sum += p[j];
    }
#pragma unroll
    for (int off = 32; off > 0; off >>= 1) sum += __shfl_xor(sum, off, 64);
    const float inv = RCPF(sum);
#pragma unroll
    for (int j = 0; j < 8; ++j) scp[0][w][l + (j << 6)] = p[j] * inv;
  }
  __syncthreads();

  if (t < 512) {
#pragma unroll
    for (int j = 0; j < 4; ++j)
      attnQ[((size_t)(b * NQ + q0 + j)) * NK + t] = f2bf(scp[0][j][t]);
  }
}

// ---------------------------------------------------------------------------
// K4: PV via MFMA bf16 (R10-proven, pre-transposed Vt).
// ---------------------------------------------------------------------------
__global__ __launch_bounds__(256) void pv_mfma_kernel(
    const unsigned short* __restrict__ attnQ, const unsigned short* __restrict__ Vt,
    const int* __restrict__ valid_lens, float* __restrict__ out) {
  const int bid = blockIdx.x;
  const int b = bid & 3;
  const int tile = bid >> 2;
  const int q0 = (tile >> 3) << 6;
  const int v0 = (tile & 7) << 6;

  __shared__ __align__(16) unsigned short Als[64 * 72];  // [q][k]
  __shared__ __align__(16) unsigned short Bls[64 * 72];  // [v][k]

  const int t = threadIdx.x;
  const int w = t >> 6, l = t & 63;
  const int wq = w >> 1, wv = w & 1;
  const int lm = l & 15;
  const int lk = (l >> 4) << 3;

  const f32x4 z = {0.f, 0.f, 0.f, 0.f};
  f32x4 acc[2][2] = {{z, z}, {z, z}};

  const int vl = valid_lens[b];
  const int nkt = (vl + 31) >> 5;

  const int sq = t >> 2, seg = t & 3;
  const unsigned short* arow = attnQ + ((size_t)(b * NQ + q0 + sq)) * NK;
  const unsigned short* brow = Vt + ((size_t)(b * NK + v0 + sq)) * NK;
  unsigned short* alds = &Als[sq * 72 + (seg << 3)];
  unsigned short* blds = &Bls[sq * 72 + (seg << 3)];

  for (int kt = 0; kt < nkt; ++kt) {
    const int k0 = kt << 5;
    *reinterpret_cast<bf16x8*>(alds) =
        *reinterpret_cast<const bf16x8*>(arow + k0 + (seg << 3));
    *reinterpret_cast<bf16x8*>(blds) =
        *reinterpret_cast<const bf16x8*>(brow + k0 + (seg << 3));
    __syncthreads();

    bf16x8 af[2], bfr[2];
#pragma unroll
    for (int mq = 0; mq < 2; ++mq)
      af[mq] = *reinterpret_cast<const bf16x8*>(
          &Als[(wq * 32 + mq * 16 + lm) * 72 + lk]);
#pragma unroll
    for (int nv = 0; nv < 2; ++nv)
      bfr[nv] = *reinterpret_cast<const bf16x8*>(
          &Bls[(wv * 32 + nv * 16 + lm) * 72 + lk]);
#pragma unroll
    for (int mq = 0; mq < 2; ++mq)
#pragma unroll
      for (int nv = 0; nv < 2; ++nv)
        acc[mq][nv] = __builtin_amdgcn_mfma_f32_16x16x32_bf16(
            af[mq], bfr[nv], acc[mq][nv], 0, 0, 0);
    __syncthreads();
  }

  // epilogue: D lane mapping col=lane&15, row=(lane>>4)*4+j  [m89-verified]
  const int rbase = (l >> 4) << 2;
#pragma unroll
  for (int mq = 0; mq < 2; ++mq) {
#pragma unroll
    for (int nv = 0; nv < 2; ++nv) {
      const int qg = q0 + wq * 32 + mq * 16 + rbase;
      const int vg = v0 + wv * 32 + nv * 16 + lm;
#pragma unroll
      for (int j = 0; j < 4; ++j)
        out[((size_t)(b * NQ + qg + j)) * DV + vg] = acc[mq][nv][j];
    }
  }
}

extern "C" void kernel_launch(void* const* d_in, const int* in_sizes, int n_in,
                              void* d_out, int out_size, void* d_ws, size_t ws_size,
                              hipStream_t stream) {
  (void)in_sizes; (void)n_in; (void)out_size; (void)ws_size;
  const float* queries = (const float*)d_in[0];
  const float* keys    = (const float*)d_in[1];
  const float* values  = (const float*)d_in[2];
  const float* Wq      = (const float*)d_in[3];
  const float* Wk      = (const float*)d_in[4];
  const float* Wv      = (const float*)d_in[5];
  const int*   vlens   = (const int*)d_in[6];
  float* out = (float*)d_out;
  float* ws = (float*)d_ws;

  // ws floats (NON-OVERLAPPING):
  //   eq       [0,        262144)
  //   ekT4     [262144,   524288)
  //   attnQ    [524288,  1048576)  (1,048,576 ushort)
  //   Vt       [1048576, 1572864)  (1,048,576 ushort)
  //   projpart [1572864, 5767168)
  float* eq   = ws;
  float* ekT4 = ws + 262144;
  unsigned short* attnQ = (unsigned short*)(ws + 524288);
  unsigned short* Vt    = (unsigned short*)(ws + 1048576);
  float* projpart = ws + 1572864;

  proj_vt_kernel<<<512, 256, 0, stream>>>(queries, keys, Wq, Wk, values, vlens,
                                          projpart, Vt);
  reduce_kernel<<<512, 256, 0, stream>>>(projpart, vlens, eq, ekT4);
  scores_softmax_kernel<<<512, 1024, 0, stream>>>(eq, ekT4, Wv, vlens, attnQ);
  pv_mfma_kernel<<<256, 256, 0, stream>>>(attnQ, Vt, vlens, out);
}

// Round 12
// 42.063 us; speedup vs baseline: 1.3826x; 1.3826x over previous
//
#include <hip/hip_runtime.h>

#ifndef __has_builtin
#define __has_builtin(x) 0
#endif

#if __has_builtin(__builtin_amdgcn_exp2f)
#define EXP2F(x) __builtin_amdgcn_exp2f(x)
#else
#define EXP2F(x) exp2f(x)
#endif
#if __has_builtin(__builtin_amdgcn_rcpf)
#define RCPF(x) __builtin_amdgcn_rcpf(x)
#else
#define RCPF(x) (1.0f / (x))
#endif

static constexpr int NB = 4, NQ = 512, NK = 512, DD = 512, HH = 128, DV = 512;
static constexpr float MASKV = -1e6f;
static constexpr float C2LOG2E = 2.885390081777926814f;  // 2*log2(e)

typedef __attribute__((ext_vector_type(8))) short bf16x8;
typedef __attribute__((ext_vector_type(4))) float f32x4;

__device__ __forceinline__ unsigned short f2bf(float x) {  // RNE f32->bf16
  unsigned int u = __float_as_uint(x);
  u += 0x7FFFu + ((u >> 16) & 1u);
  return (unsigned short)(u >> 16);
}
__device__ __forceinline__ float bf2f(unsigned short h) {
  return __uint_as_float(((unsigned int)h) << 16);
}
// split x = hi + lo (lo exact residual, then rounded): |x-hi-lo| <= 2^-18|x|
__device__ __forceinline__ void split2(float x, unsigned short& hi, unsigned short& lo) {
  hi = f2bf(x);
  lo = f2bf(x - bf2f(hi));
}

// ---------------------------------------------------------------------------
// K1: 512 blocks.
//  bid 0..255  : projection via split-bf16 MFMA, tile 16 rows x 128 h, full K.
//                rows 0..2047 = queries -> eq[row][h]=exp2(C*p)
//                rows 2048..  = keys    -> ekT4[b][h4][k][4] (LDS-bounce
//                transpose in epilogue). D = Ah*Wh + Al*Wh + Ah*Wl.
//                Fragment geometry mirrors pv_mfma (72-ushort rows, proven).
//  bid 256..511: V transpose -> Vt[b][v][k] bf16 (R10-proven).
// ---------------------------------------------------------------------------
__global__ __launch_bounds__(256) void proj_mfma_vt_kernel(
    const float* __restrict__ queries, const float* __restrict__ keys,
    const float* __restrict__ Wq, const float* __restrict__ Wk,
    const float* __restrict__ values, const int* __restrict__ valid_lens,
    float* __restrict__ eq, float* __restrict__ ekT4,
    unsigned short* __restrict__ Vt) {
  __shared__ __align__(16) unsigned short smem_us[20736];  // 41.5 KB
  const int bid = blockIdx.x;
  const int t = threadIdx.x;

  if (bid < 256) {
    const int row0 = bid << 4;
    const bool isK = row0 >= 2048;
    int b = 0, kloc = 0;
    const float* inb;
    const float* W;
    if (isK) {
      const int local = row0 - 2048;
      b = local >> 9;
      kloc = local & 511;
      if (kloc >= valid_lens[b]) return;  // fully-masked tile, never read
      inb = keys + (size_t)local * DD;
      W = Wk;
    } else {
      inb = queries + (size_t)row0 * DD;
      W = Wq;
    }

    unsigned short* Ah = smem_us;          // [16][72]
    unsigned short* Al = smem_us + 1152;   // [16][72]
    unsigned short* Wh = smem_us + 2304;   // [128][72] ([h][k])
    unsigned short* Wl = smem_us + 11520;  // [128][72]

    const int w = t >> 6, l = t & 63;
    const int lm = l & 15;
    const int lk8 = (l >> 4) << 3;

    const f32x4 z = {0.f, 0.f, 0.f, 0.f};
    f32x4 acc[2] = {z, z};  // col tiles h = 32w+0..15, 32w+16..31

    const int ar = t >> 4, ac4 = (t & 15) << 2;        // A staging: row, k4
    const int wh = t & 127, wkg = (t >> 7) << 5;       // W staging: h, k-group

    for (int kt = 0; kt < 8; ++kt) {
      const int k0 = kt << 6;
      {  // stage A: 16 rows x 64 k, split hi/lo, pack k-pairs into u32
        const float4 v = *reinterpret_cast<const float4*>(inb + (size_t)ar * DD + k0 + ac4);
        unsigned short h0, h1, h2, h3, l0, l1, l2, l3;
        split2(v.x, h0, l0); split2(v.y, h1, l1);
        split2(v.z, h2, l2); split2(v.w, h3, l3);
        uint2 ph = make_uint2((unsigned int)h0 | ((unsigned int)h1 << 16),
                              (unsigned int)h2 | ((unsigned int)h3 << 16));
        uint2 pl = make_uint2((unsigned int)l0 | ((unsigned int)l1 << 16),
                              (unsigned int)l2 | ((unsigned int)l3 << 16));
        *reinterpret_cast<uint2*>(Ah + ar * 72 + ac4) = ph;
        *reinterpret_cast<uint2*>(Al + ar * 72 + ac4) = pl;
      }
      {  // stage W transposed: [h][k], 32 k per thread (coalesced b32 loads)
        unsigned int hw[16], lw[16];
#pragma unroll
        for (int i = 0; i < 16; ++i) {
          const float w0 = W[(size_t)(k0 + wkg + 2 * i) * HH + wh];
          const float w1 = W[(size_t)(k0 + wkg + 2 * i + 1) * HH + wh];
          unsigned short a0, a1, b0, b1;
          split2(w0, a0, b0); split2(w1, a1, b1);
          hw[i] = (unsigned int)a0 | ((unsigned int)a1 << 16);
          lw[i] = (unsigned int)b0 | ((unsigned int)b1 << 16);
        }
        unsigned int* dh = reinterpret_cast<unsigned int*>(Wh + wh * 72 + wkg);
        unsigned int* dl = reinterpret_cast<unsigned int*>(Wl + wh * 72 + wkg);
#pragma unroll
        for (int i = 0; i < 4; ++i) {
          *reinterpret_cast<uint4*>(dh + 4 * i) =
              make_uint4(hw[4 * i], hw[4 * i + 1], hw[4 * i + 2], hw[4 * i + 3]);
          *reinterpret_cast<uint4*>(dl + 4 * i) =
              make_uint4(lw[4 * i], lw[4 * i + 1], lw[4 * i + 2], lw[4 * i + 3]);
        }
      }
      __syncthreads();

#pragma unroll
      for (int kh = 0; kh < 2; ++kh) {  // k halves 0..31 / 32..63
        const int ko = lk8 + (kh << 5);
        const bf16x8 ah = *reinterpret_cast<const bf16x8*>(Ah + lm * 72 + ko);
        const bf16x8 al = *reinterpret_cast<const bf16x8*>(Al + lm * 72 + ko);
#pragma unroll
        for (int c = 0; c < 2; ++c) {
          const int hrow = (w << 5) + (c << 4) + lm;
          const bf16x8 bh = *reinterpret_cast<const bf16x8*>(Wh + hrow * 72 + ko);
          const bf16x8 bl = *reinterpret_cast<const bf16x8*>(Wl + hrow * 72 + ko);
          acc[c] = __builtin_amdgcn_mfma_f32_16x16x32_bf16(ah, bh, acc[c], 0, 0, 0);
          acc[c] = __builtin_amdgcn_mfma_f32_16x16x32_bf16(al, bh, acc[c], 0, 0, 0);
          acc[c] = __builtin_amdgcn_mfma_f32_16x16x32_bf16(ah, bl, acc[c], 0, 0, 0);
        }
      }
      __syncthreads();
    }

    // epilogue: D mapping col=lane&15, row=(lane>>4)*4+j  [m89-verified]
    const int rb = (l >> 4) << 2;
    if (!isK) {
#pragma unroll
      for (int c = 0; c < 2; ++c) {
        const int h = (w << 5) + (c << 4) + lm;
#pragma unroll
        for (int j = 0; j < 4; ++j)
          eq[(size_t)(row0 + rb + j) * HH + h] = EXP2F(acc[c][j] * C2LOG2E);
      }
    } else {
      float* tile = reinterpret_cast<float*>(smem_us);  // [16][132] f32
#pragma unroll
      for (int c = 0; c < 2; ++c) {
        const int h = (w << 5) + (c << 4) + lm;
#pragma unroll
        for (int j = 0; j < 4; ++j)
          tile[(rb + j) * 132 + h] = EXP2F(acc[c][j] * C2LOG2E);
      }
      __syncthreads();
#pragma unroll
      for (int i = 0; i < 2; ++i) {
        const int idx = t + (i << 8);
        const int k = idx & 15, h4 = idx >> 4;  // h4 0..31
        const float4 v = *reinterpret_cast<const float4*>(tile + k * 132 + (h4 << 2));
        *reinterpret_cast<float4*>(
            ekT4 + ((((size_t)b * 32 + h4) << 9) + kloc + k) * 4) = v;
      }
    }
  } else {
    // V transpose (R10-proven)
    unsigned short (*tl)[72] = reinterpret_cast<unsigned short (*)[72]>(smem_us);
    const int vb = bid - 256;
    const int b = vb >> 6;
    const int tile = vb & 63;
    const int k0 = (tile >> 3) << 6;
    const int v0 = (tile & 7) << 6;
    const int kr = t >> 4, c4 = (t & 15) << 2;
#pragma unroll
    for (int pp = 0; pp < 4; ++pp) {
      const int k = kr + (pp << 4);
      const float4 v = *reinterpret_cast<const float4*>(
          values + ((size_t)(b * NK + k0 + k)) * DV + v0 + c4);
      tl[k][c4 + 0] = f2bf(v.x); tl[k][c4 + 1] = f2bf(v.y);
      tl[k][c4 + 2] = f2bf(v.z); tl[k][c4 + 3] = f2bf(v.w);
    }
    __syncthreads();
    const int vr = t >> 2, seg = t & 3;
    unsigned int pk[8];
#pragma unroll
    for (int i = 0; i < 8; ++i) {
      const int kc = (seg << 4) + (i << 1);
      pk[i] = (unsigned int)tl[kc][vr] | ((unsigned int)tl[kc + 1][vr] << 16);
    }
    unsigned short* dst = Vt + ((size_t)(b * NK + v0 + vr)) * NK + k0 + (seg << 4);
    *reinterpret_cast<uint4*>(dst) = make_uint4(pk[0], pk[1], pk[2], pk[3]);
    *reinterpret_cast<uint4*>(dst + 8) = make_uint4(pk[4], pk[5], pk[6], pk[7]);
  }
}

// ---------------------------------------------------------------------------
// K2: scores + masked softmax (R10-proven). 1024 threads, h-split x2.
// Block = (b, 4 q-rows), 512 blocks; thread = (key kk, h-half hh).
// score = -2*sum_h w_h/(1+eq*ek). Output attnQ[b][q][k] bf16.
// ---------------------------------------------------------------------------
__global__ __launch_bounds__(1024) void scores_softmax_kernel(
    const float* __restrict__ eq, const float* __restrict__ ekT4,
    const float* __restrict__ Wv, const int* __restrict__ valid_lens,
    unsigned short* __restrict__ attnQ) {
  const int b = blockIdx.x >> 7;
  const int q0 = (blockIdx.x & 127) << 2;
  const int t = threadIdx.x;
  const int kk = t & 511, hh = t >> 9;

  __shared__ __align__(16) float qs[4][HH];
  __shared__ __align__(16) float wv[HH];
  __shared__ __align__(16) float scp[2][4][NK];  // 16 KB partials

  if (t < 512) {
    qs[t >> 7][t & 127] = eq[((size_t)(b * NQ + q0 + (t >> 7))) * HH + (t & 127)];
  } else if (t < 640) {
    wv[t - 512] = Wv[t - 512];
  }
  __syncthreads();

  const int vl = valid_lens[b];
  float s0 = 0.f, s1 = 0.f, s2 = 0.f, s3 = 0.f;

  if (kk < vl) {
    const float* ekb4 = ekT4 + (((size_t)(b * 32 + hh * 16) << 9) + kk) * 4;
#pragma unroll 8
    for (int i = 0; i < 16; ++i) {
      const float4 e4 = *reinterpret_cast<const float4*>(ekb4 + ((size_t)i << 11));
      const int h = (hh * 16 + i) << 2;
      const float4 w4 = *reinterpret_cast<const float4*>(&wv[h]);
      const float4 qa = *reinterpret_cast<const float4*>(&qs[0][h]);
      const float4 qb = *reinterpret_cast<const float4*>(&qs[1][h]);
      const float4 qc = *reinterpret_cast<const float4*>(&qs[2][h]);
      const float4 qd = *reinterpret_cast<const float4*>(&qs[3][h]);
      float d, r;
      d = fmaf(qa.x, e4.x, 1.f); r = RCPF(d); s0 = fmaf(w4.x, r, s0);
      d = fmaf(qa.y, e4.y, 1.f); r = RCPF(d); s0 = fmaf(w4.y, r, s0);
      d = fmaf(qa.z, e4.z, 1.f); r = RCPF(d); s0 = fmaf(w4.z, r, s0);
      d = fmaf(qa.w, e4.w, 1.f); r = RCPF(d); s0 = fmaf(w4.w, r, s0);
      d = fmaf(qb.x, e4.x, 1.f); r = RCPF(d); s1 = fmaf(w4.x, r, s1);
      d = fmaf(qb.y, e4.y, 1.f); r = RCPF(d); s1 = fmaf(w4.y, r, s1);
      d = fmaf(qb.z, e4.z, 1.f); r = RCPF(d); s1 = fmaf(w4.z, r, s1);
      d = fmaf(qb.w, e4.w, 1.f); r = RCPF(d); s1 = fmaf(w4.w, r, s1);
      d = fmaf(qc.x, e4.x, 1.f); r = RCPF(d); s2 = fmaf(w4.x, r, s2);
      d = fmaf(qc.y, e4.y, 1.f); r = RCPF(d); s2 = fmaf(w4.y, r, s2);
      d = fmaf(qc.z, e4.z, 1.f); r = RCPF(d); s2 = fmaf(w4.z, r, s2);
      d = fmaf(qc.w, e4.w, 1.f); r = RCPF(d); s2 = fmaf(w4.w, r, s2);
      d = fmaf(qd.x, e4.x, 1.f); r = RCPF(d); s3 = fmaf(w4.x, r, s3);
      d = fmaf(qd.y, e4.y, 1.f); r = RCPF(d); s3 = fmaf(w4.y, r, s3);
      d = fmaf(qd.z, e4.z, 1.f); r = RCPF(d); s3 = fmaf(w4.z, r, s3);
      d = fmaf(qd.w, e4.w, 1.f); r = RCPF(d); s3 = fmaf(w4.w, r, s3);
    }
  }
  scp[hh][0][kk] = s0;
  scp[hh][1][kk] = s1;
  scp[hh][2][kk] = s2;
  scp[hh][3][kk] = s3;
  __syncthreads();

  if (t < 256) {
    const int w = t >> 6, l = t & 63;
    float v[8];
#pragma unroll
    for (int j = 0; j < 8; ++j) {
      const int k = l + (j << 6);
      const float sv = scp[0][w][k] + scp[1][w][k];
      v[j] = (k < vl) ? (-2.f * sv) : MASKV;
    }
    float m = v[0];
#pragma unroll
    for (int j = 1; j < 8; ++j) m = fmaxf(m, v[j]);
#pragma unroll
    for (int off = 32; off > 0; off >>= 1) m = fmaxf(m, __shfl_xor(m, off, 64));
    float p[8], sum = 0.f;
#pragma unroll
    for (int j = 0; j < 8; ++j) {
      p[j] = __expf(v[j] - m);  // masked: underflows to exactly 0
      sum += p[j];
    }
#pragma unroll
    for (int off = 32; off > 0; off >>= 1) sum += __shfl_xor(sum, off, 64);
    const float inv = RCPF(sum);
#pragma unroll
    for (int j = 0; j < 8; ++j) scp[0][w][l + (j << 6)] = p[j] * inv;
  }
  __syncthreads();

  if (t < 512) {
#pragma unroll
    for (int j = 0; j < 4; ++j)
      attnQ[((size_t)(b * NQ + q0 + j)) * NK + t] = f2bf(scp[0][j][t]);
  }
}

// ---------------------------------------------------------------------------
// K3: PV via MFMA bf16 (R10-proven, pre-transposed Vt).
// ---------------------------------------------------------------------------
__global__ __launch_bounds__(256) void pv_mfma_kernel(
    const unsigned short* __restrict__ attnQ, const unsigned short* __restrict__ Vt,
    const int* __restrict__ valid_lens, float* __restrict__ out) {
  const int bid = blockIdx.x;
  const int b = bid & 3;
  const int tile = bid >> 2;
  const int q0 = (tile >> 3) << 6;
  const int v0 = (tile & 7) << 6;

  __shared__ __align__(16) unsigned short Als[64 * 72];  // [q][k]
  __shared__ __align__(16) unsigned short Bls[64 * 72];  // [v][k]

  const int t = threadIdx.x;
  const int w = t >> 6, l = t & 63;
  const int wq = w >> 1, wv = w & 1;
  const int lm = l & 15;
  const int lk = (l >> 4) << 3;

  const f32x4 z = {0.f, 0.f, 0.f, 0.f};
  f32x4 acc[2][2] = {{z, z}, {z, z}};

  const int vl = valid_lens[b];
  const int nkt = (vl + 31) >> 5;

  const int sq = t >> 2, seg = t & 3;
  const unsigned short* arow = attnQ + ((size_t)(b * NQ + q0 + sq)) * NK;
  const unsigned short* brow = Vt + ((size_t)(b * NK + v0 + sq)) * NK;
  unsigned short* alds = &Als[sq * 72 + (seg << 3)];
  unsigned short* blds = &Bls[sq * 72 + (seg << 3)];

  for (int kt = 0; kt < nkt; ++kt) {
    const int k0 = kt << 5;
    *reinterpret_cast<bf16x8*>(alds) =
        *reinterpret_cast<const bf16x8*>(arow + k0 + (seg << 3));
    *reinterpret_cast<bf16x8*>(blds) =
        *reinterpret_cast<const bf16x8*>(brow + k0 + (seg << 3));
    __syncthreads();

    bf16x8 af[2], bfr[2];
#pragma unroll
    for (int mq = 0; mq < 2; ++mq)
      af[mq] = *reinterpret_cast<const bf16x8*>(
          &Als[(wq * 32 + mq * 16 + lm) * 72 + lk]);
#pragma unroll
    for (int nv = 0; nv < 2; ++nv)
      bfr[nv] = *reinterpret_cast<const bf16x8*>(
          &Bls[(wv * 32 + nv * 16 + lm) * 72 + lk]);
#pragma unroll
    for (int mq = 0; mq < 2; ++mq)
#pragma unroll
      for (int nv = 0; nv < 2; ++nv)
        acc[mq][nv] = __builtin_amdgcn_mfma_f32_16x16x32_bf16(
            af[mq], bfr[nv], acc[mq][nv], 0, 0, 0);
    __syncthreads();
  }

  const int rbase = (l >> 4) << 2;
#pragma unroll
  for (int mq = 0; mq < 2; ++mq) {
#pragma unroll
    for (int nv = 0; nv < 2; ++nv) {
      const int qg = q0 + wq * 32 + mq * 16 + rbase;
      const int vg = v0 + wv * 32 + nv * 16 + lm;
#pragma unroll
      for (int j = 0; j < 4; ++j)
        out[((size_t)(b * NQ + qg + j)) * DV + vg] = acc[mq][nv][j];
    }
  }
}

extern "C" void kernel_launch(void* const* d_in, const int* in_sizes, int n_in,
                              void* d_out, int out_size, void* d_ws, size_t ws_size,
                              hipStream_t stream) {
  (void)in_sizes; (void)n_in; (void)out_size; (void)ws_size;
  const float* queries = (const float*)d_in[0];
  const float* keys    = (const float*)d_in[1];
  const float* values  = (const float*)d_in[2];
  const float* Wq      = (const float*)d_in[3];
  const float* Wk      = (const float*)d_in[4];
  const float* Wv      = (const float*)d_in[5];
  const int*   vlens   = (const int*)d_in[6];
  float* out = (float*)d_out;
  float* ws = (float*)d_ws;

  // ws floats (NON-OVERLAPPING):
  //   eq    [0,        262144)
  //   ekT4  [262144,   524288)
  //   attnQ [524288,  1048576)  (1,048,576 ushort)
  //   Vt    [1048576, 1572864)  (1,048,576 ushort)
  float* eq   = ws;
  float* ekT4 = ws + 262144;
  unsigned short* attnQ = (unsigned short*)(ws + 524288);
  unsigned short* Vt    = (unsigned short*)(ws + 1048576);

  proj_mfma_vt_kernel<<<512, 256, 0, stream>>>(queries, keys, Wq, Wk, values,
                                               vlens, eq, ekT4, Vt);
  scores_softmax_kernel<<<512, 1024, 0, stream>>>(eq, ekT4, Wv, vlens, attnQ);
  pv_mfma_kernel<<<256, 256, 0, stream>>>(attnQ, Vt, vlens, out);
}